// Round 5
// baseline (1074.553 us; speedup 1.0000x reference)
//
#include <hip/hip_runtime.h>

// ============================================================================
// TinyTransformerBlock via split-precision bf16x3 MFMA (gfx950).
// C = ah*bh + ah*bl + al*bh in fp32 AGPRs (al*bl dropped, ~2^-18 rel).
// Two GEMM engines:
//  - gemm256: 256x256 tile, BK=32, 8 waves, 128KB LDS 2-deep dbuf,
//    hi/lo interleaved rows (128B) with 8-slot XOR swizzle (bank-balanced),
//    4 phases/K-tile with counted vmcnt(2) + raw barriers + setprio (T2-T5).
//    Used for QKV-fused (N=3072), scores, FFN1 (grids >= 256 blocks).
//  - gemm_bf16x3: proven 128x128 m97-style kernel for N=1024 GEMMs
//    (ctx, Wo, FFN2) where 256^2 grids would underfill 256 CUs.
// ============================================================================

#define EPS 1e-5f
constexpr int D   = 1024;
constexpr int DFF = 4096;
constexpr int NB  = 4;
constexpr int S   = 2048;
constexpr int M   = NB * S;  // 8192

typedef __bf16 bf16x8 __attribute__((ext_vector_type(8)));
typedef float  f32x4  __attribute__((ext_vector_type(4)));

__device__ __forceinline__ ushort f2bf(float f) {  // RTNE to bf16
  uint u = __builtin_bit_cast(uint, f);
  return (ushort)((u + 0x7fffu + ((u >> 16) & 1u)) >> 16);
}
__device__ __forceinline__ float bf2f(ushort h) {
  return __builtin_bit_cast(float, (uint)h << 16);
}
__device__ __forceinline__ void split(float f, ushort& h, ushort& l) {
  h = f2bf(f);
  l = f2bf(f - bf2f(h));
}

#define GLOAD16(g, l)                                                     \
  __builtin_amdgcn_global_load_lds(                                       \
      (const __attribute__((address_space(1))) void*)(g),                 \
      (__attribute__((address_space(3))) void*)(l), 16, 0, 0)

#define LD8(base, off) \
  __builtin_bit_cast(bf16x8, *reinterpret_cast<const uint4*>((base) + (off)))

// ---------------- LayerNorm -> bf16 hi/lo ------------------------------------
__global__ __launch_bounds__(256) void ln_kernel(const float* __restrict__ x,
                                                 const float* __restrict__ w,
                                                 const float* __restrict__ b,
                                                 ushort* __restrict__ oh,
                                                 ushort* __restrict__ ol) {
  const int row = blockIdx.x;
  const int t   = threadIdx.x;
  const float4 v = reinterpret_cast<const float4*>(x + (size_t)row * D)[t];
  float s  = v.x + v.y + v.z + v.w;
  float sq = v.x * v.x + v.y * v.y + v.z * v.z + v.w * v.w;
#pragma unroll
  for (int off = 32; off > 0; off >>= 1) {
    s  += __shfl_down(s, off);
    sq += __shfl_down(sq, off);
  }
  __shared__ float red[8];
  if ((t & 63) == 0) { red[t >> 6] = s; red[(t >> 6) + 4] = sq; }
  __syncthreads();
  if (t == 0) {
    float ts = red[0] + red[1] + red[2] + red[3];
    float tq = red[4] + red[5] + red[6] + red[7];
    float mu  = ts * (1.0f / D);
    float var = tq * (1.0f / D) - mu * mu;
    red[0] = mu;
    red[1] = rsqrtf(var + EPS);
  }
  __syncthreads();
  const float mu = red[0], rs = red[1];
  const float4 wv = reinterpret_cast<const float4*>(w)[t];
  const float4 bv = reinterpret_cast<const float4*>(b)[t];
  float o0 = (v.x - mu) * rs * wv.x + bv.x;
  float o1 = (v.y - mu) * rs * wv.y + bv.y;
  float o2 = (v.z - mu) * rs * wv.z + bv.z;
  float o3 = (v.w - mu) * rs * wv.w + bv.w;
  ushort4 hh, ll;
  split(o0, hh.x, ll.x); split(o1, hh.y, ll.y);
  split(o2, hh.z, ll.z); split(o3, hh.w, ll.w);
  *reinterpret_cast<ushort4*>(oh + (size_t)row * D + t * 4) = hh;
  *reinterpret_cast<ushort4*>(ol + (size_t)row * D + t * 4) = ll;
}

// ---------------- Softmax (scale folded) -> bf16 hi/lo -----------------------
__global__ __launch_bounds__(256) void softmax_kernel(const float* __restrict__ sc,
                                                      ushort* __restrict__ oh,
                                                      ushort* __restrict__ ol) {
  const size_t row = blockIdx.x;
  const float* p = sc + row * (size_t)S;
  const int t = threadIdx.x;
  constexpr float scale = 0.03125f;  // 1/sqrt(1024)
  float4 a = reinterpret_cast<const float4*>(p)[t];
  float4 b = reinterpret_cast<const float4*>(p)[t + 256];
  a.x *= scale; a.y *= scale; a.z *= scale; a.w *= scale;
  b.x *= scale; b.y *= scale; b.z *= scale; b.w *= scale;
  float m = fmaxf(fmaxf(fmaxf(a.x, a.y), fmaxf(a.z, a.w)),
                  fmaxf(fmaxf(b.x, b.y), fmaxf(b.z, b.w)));
#pragma unroll
  for (int off = 32; off > 0; off >>= 1) m = fmaxf(m, __shfl_xor(m, off));
  __shared__ float redm[4];
  __shared__ float reds[4];
  if ((t & 63) == 0) redm[t >> 6] = m;
  __syncthreads();
  m = fmaxf(fmaxf(redm[0], redm[1]), fmaxf(redm[2], redm[3]));
  a.x = __expf(a.x - m); a.y = __expf(a.y - m);
  a.z = __expf(a.z - m); a.w = __expf(a.w - m);
  b.x = __expf(b.x - m); b.y = __expf(b.y - m);
  b.z = __expf(b.z - m); b.w = __expf(b.w - m);
  float s = a.x + a.y + a.z + a.w + b.x + b.y + b.z + b.w;
#pragma unroll
  for (int off = 32; off > 0; off >>= 1) s += __shfl_xor(s, off);
  if ((t & 63) == 0) reds[t >> 6] = s;
  __syncthreads();
  s = reds[0] + reds[1] + reds[2] + reds[3];
  const float inv = 1.0f / s;
  ushort4 ha, la, hb, lb;
  split(a.x * inv, ha.x, la.x); split(a.y * inv, ha.y, la.y);
  split(a.z * inv, ha.z, la.z); split(a.w * inv, ha.w, la.w);
  split(b.x * inv, hb.x, lb.x); split(b.y * inv, hb.y, lb.y);
  split(b.z * inv, hb.z, lb.z); split(b.w * inv, hb.w, lb.w);
  ushort* ph = oh + row * (size_t)S;
  ushort* pl = ol + row * (size_t)S;
  *reinterpret_cast<ushort4*>(ph + t * 4)        = ha;
  *reinterpret_cast<ushort4*>(ph + 1024 + t * 4) = hb;
  *reinterpret_cast<ushort4*>(pl + t * 4)        = la;
  *reinterpret_cast<ushort4*>(pl + 1024 + t * 4) = lb;
}

// ---------------- Transpose fp32 [R][C] -> bf16 hi/lo [C][R] -----------------
__global__ __launch_bounds__(256) void transpose_conv(const float* __restrict__ in,
                                                      ushort* __restrict__ oh,
                                                      ushort* __restrict__ ol,
                                                      int R, int C,
                                                      long long sIn, long long sOut) {
  __shared__ float tile[32][33];
  const int bz = blockIdx.z;
  const float* ip = in + (size_t)bz * sIn;
  ushort* ph = oh + (size_t)bz * sOut;
  ushort* pl = ol + (size_t)bz * sOut;
  const int c0 = blockIdx.x * 32, r0 = blockIdx.y * 32;
  const int tx = threadIdx.x & 31, ty = threadIdx.x >> 5;
#pragma unroll
  for (int i = 0; i < 4; ++i)
    tile[ty + 8 * i][tx] = ip[(size_t)(r0 + ty + 8 * i) * C + c0 + tx];
  __syncthreads();
#pragma unroll
  for (int i = 0; i < 4; ++i) {
    float v = tile[tx][ty + 8 * i];
    ushort h, l;
    split(v, h, l);
    const size_t o = (size_t)(c0 + ty + 8 * i) * R + r0 + tx;
    ph[o] = h;
    pl[o] = l;
  }
}

// ---------------- Transpose ushort pair [R][C] -> [C][R] ---------------------
__global__ __launch_bounds__(256) void transpose_bf(const ushort* __restrict__ ih,
                                                    const ushort* __restrict__ il,
                                                    ushort* __restrict__ oh,
                                                    ushort* __restrict__ ol,
                                                    int R, int C,
                                                    long long sIn, long long sOut) {
  __shared__ ushort th[32][34];
  __shared__ ushort tl[32][34];
  const int bz = blockIdx.z;
  const ushort* ph = ih + (size_t)bz * sIn;
  const ushort* pl = il + (size_t)bz * sIn;
  ushort* qh = oh + (size_t)bz * sOut;
  ushort* ql = ol + (size_t)bz * sOut;
  const int c0 = blockIdx.x * 32, r0 = blockIdx.y * 32;
  const int tx = threadIdx.x & 31, ty = threadIdx.x >> 5;
#pragma unroll
  for (int i = 0; i < 4; ++i) {
    const size_t src = (size_t)(r0 + ty + 8 * i) * C + c0 + tx;
    th[ty + 8 * i][tx] = ph[src];
    tl[ty + 8 * i][tx] = pl[src];
  }
  __syncthreads();
#pragma unroll
  for (int i = 0; i < 4; ++i) {
    const size_t o = (size_t)(c0 + ty + 8 * i) * R + r0 + tx;
    qh[o] = th[tx][ty + 8 * i];
    ql[o] = tl[tx][ty + 8 * i];
  }
}

// ================= 256x256 pipelined bf16x3 GEMM (T2+T3+T4+T5) ===============
// A:[M][K] h/l.  Bt:[N][K] h/l.  8 waves (2x4), per-wave 128x64.
// LDS rows = 128B: [hi k0..31 | lo k0..31] as 8x16B slots, slot' = slot^(row&7).
// Staging (global_load_lds, linear dest): thread tid, round rr (A:0-3, B:0-3):
//   LDS byte = rr*8192 + tid*16 -> row = rr*64 + tid/8, slot' = tid&7 ->
//   logical slot = slot'^(row&7) -> hilo = slot>>2, kgran = slot&3.
// Schedule/K-tile: P0{issue 2 A-loads; vmcnt(2); bar; read B(8)+A01(4); bar;
// 24 MFMA; bar} P1{read A23; issue A23-loads; bar; 24 MFMA; bar} P2/P3 same
// with B-loads. vmcnt never 0 in steady state (2 loads ride across barriers).
template <bool HAS_BIAS, bool RELU, bool WRITE_F32, int NSEG>
__global__ __launch_bounds__(512, 2) void gemm256(
    const ushort* __restrict__ Ah, const ushort* __restrict__ Al,
    const ushort* __restrict__ Bth, const ushort* __restrict__ Btl,
    const float* __restrict__ b0, const float* __restrict__ b1,
    const float* __restrict__ b2, float* __restrict__ Cf,
    ushort* __restrict__ Ch0, ushort* __restrict__ Cl0,
    ushort* __restrict__ Ch1, ushort* __restrict__ Cl1,
    ushort* __restrict__ Ch2, ushort* __restrict__ Cl2,
    int N, int K, int ostride, long long sA, long long sB, long long sC) {
  __shared__ __align__(16) ushort sAb[2][256 * 64];
  __shared__ __align__(16) ushort sBb[2][256 * 64];

  const int bz = blockIdx.z;
  const size_t aof = (size_t)bz * sA, bof = (size_t)bz * sB, cof = (size_t)bz * sC;

  // XCD-aware chunked swizzle within z-slice (nwg%8==0 for all launches here)
  const int gx = gridDim.x;
  const int nwg = gx * gridDim.y;
  int lin = blockIdx.y * gx + blockIdx.x;
  lin = (lin & 7) * (nwg >> 3) + (lin >> 3);
  const int bm = (lin / gx) * 256;
  const int bn = (lin % gx) * 256;

  const int tid = threadIdx.x;
  const int lane = tid & 63, w = tid >> 6;
  const int wr = (w >> 2) * 128, wc = (w & 3) * 64;
  const int fr = lane & 15, fc = lane >> 4;

  // ---- staging decode (same for all rounds; row&7 independent of round) ----
  const int srow  = tid >> 3;                 // 0..63
  const int slot  = (tid & 7) ^ (srow & 7);   // logical slot at this lane's dest
  const int hilo  = slot >> 2;
  const int kg    = slot & 3;
  const ushort* gA = (hilo ? Al : Ah) + aof + (size_t)(bm + srow) * K + kg * 8;
  const ushort* gB = (hilo ? Btl : Bth) + bof + (size_t)(bn + srow) * K + kg * 8;
  const size_t rstep = (size_t)64 * K;        // 64 rows per 8KB round
  const int dsto = tid * 16;                  // linear LDS byte offset in round

  // ---- swizzled ds_read byte offsets ----
  int aoff[8][2], boff[4][2];
#pragma unroll
  for (int i = 0; i < 8; ++i) {
    const int row = wr + i * 16 + fr;
#pragma unroll
    for (int h = 0; h < 2; ++h)
      aoff[i][h] = row * 128 + (((h * 4 + fc) ^ (row & 7)) * 16);
  }
#pragma unroll
  for (int j = 0; j < 4; ++j) {
    const int row = wc + j * 16 + fr;
#pragma unroll
    for (int h = 0; h < 2; ++h)
      boff[j][h] = row * 128 + (((h * 4 + fc) ^ (row & 7)) * 16);
  }

  f32x4 acc[8][4];
  const f32x4 zero = {0.f, 0.f, 0.f, 0.f};
#pragma unroll
  for (int i = 0; i < 8; ++i)
#pragma unroll
    for (int j = 0; j < 4; ++j) acc[i][j] = zero;

  const int nt = K >> 5;

  // ---- prologue: stage tile 0 -> buf 0 ----
  {
    char* dA = (char*)(&sAb[0][0]) + dsto;
    char* dB = (char*)(&sBb[0][0]) + dsto;
#pragma unroll
    for (int rr = 0; rr < 4; ++rr) {
      GLOAD16(gA + rr * rstep, dA + rr * 8192);
      GLOAD16(gB + rr * rstep, dB + rr * 8192);
    }
  }

#define MFMA6(ii, xh, xl, jj)                                                 \
  acc[ii][jj] = __builtin_amdgcn_mfma_f32_16x16x32_bf16(xh, bh##jj, acc[ii][jj], 0, 0, 0); \
  acc[ii][jj] = __builtin_amdgcn_mfma_f32_16x16x32_bf16(xh, bl##jj, acc[ii][jj], 0, 0, 0); \
  acc[ii][jj] = __builtin_amdgcn_mfma_f32_16x16x32_bf16(xl, bh##jj, acc[ii][jj], 0, 0, 0);

#define MFMA_PAIR(i0, i1, xh, xl, yh, yl)                                     \
  MFMA6(i0, xh, xl, 0) MFMA6(i1, yh, yl, 0)                                   \
  MFMA6(i0, xh, xl, 1) MFMA6(i1, yh, yl, 1)                                   \
  MFMA6(i0, xh, xl, 2) MFMA6(i1, yh, yl, 2)                                   \
  MFMA6(i0, xh, xl, 3) MFMA6(i1, yh, yl, 3)

  for (int t = 0; t < nt; ++t) {
    const int p = t & 1, q = p ^ 1;
    const bool pf = (t + 1 < nt);
    const int kkn = (t + 1) << 5;
    const ushort* gAn = gA + kkn;
    const ushort* gBn = gB + kkn;
    char* dAq = (char*)(&sAb[q][0]) + dsto;
    char* dBq = (char*)(&sBb[q][0]) + dsto;
    const char* lA = (const char*)(&sAb[p][0]);
    const char* lB = (const char*)(&sBb[p][0]);

    // ---------- P0 ----------
    if (pf) {
      GLOAD16(gAn + 0 * rstep, dAq + 0 * 8192);
      GLOAD16(gAn + 1 * rstep, dAq + 1 * 8192);
      asm volatile("s_waitcnt vmcnt(2)" ::: "memory");
    } else {
      asm volatile("s_waitcnt vmcnt(0)" ::: "memory");
    }
    __builtin_amdgcn_s_barrier();

    bf16x8 bh0 = LD8(lB, boff[0][0]), bl0 = LD8(lB, boff[0][1]);
    bf16x8 bh1 = LD8(lB, boff[1][0]), bl1 = LD8(lB, boff[1][1]);
    bf16x8 bh2 = LD8(lB, boff[2][0]), bl2 = LD8(lB, boff[2][1]);
    bf16x8 bh3 = LD8(lB, boff[3][0]), bl3 = LD8(lB, boff[3][1]);
    bf16x8 a0h = LD8(lA, aoff[0][0]), a0l = LD8(lA, aoff[0][1]);
    bf16x8 a1h = LD8(lA, aoff[1][0]), a1l = LD8(lA, aoff[1][1]);
    __builtin_amdgcn_s_barrier();
    __builtin_amdgcn_s_setprio(1);
    MFMA_PAIR(0, 1, a0h, a0l, a1h, a1l)
    __builtin_amdgcn_s_setprio(0);
    __builtin_amdgcn_s_barrier();

    // ---------- P1 ----------
    {
      bf16x8 a2h = LD8(lA, aoff[2][0]), a2l = LD8(lA, aoff[2][1]);
      bf16x8 a3h = LD8(lA, aoff[3][0]), a3l = LD8(lA, aoff[3][1]);
      if (pf) {
        GLOAD16(gAn + 2 * rstep, dAq + 2 * 8192);
        GLOAD16(gAn + 3 * rstep, dAq + 3 * 8192);
      }
      __builtin_amdgcn_s_barrier();
      __builtin_amdgcn_s_setprio(1);
      MFMA_PAIR(2, 3, a2h, a2l, a3h, a3l)
      __builtin_amdgcn_s_setprio(0);
      __builtin_amdgcn_s_barrier();
    }
    // ---------- P2 ----------
    {
      bf16x8 a4h = LD8(lA, aoff[4][0]), a4l = LD8(lA, aoff[4][1]);
      bf16x8 a5h = LD8(lA, aoff[5][0]), a5l = LD8(lA, aoff[5][1]);
      if (pf) {
        GLOAD16(gBn + 0 * rstep, dBq + 0 * 8192);
        GLOAD16(gBn + 1 * rstep, dBq + 1 * 8192);
      }
      __builtin_amdgcn_s_barrier();
      __builtin_amdgcn_s_setprio(1);
      MFMA_PAIR(4, 5, a4h, a4l, a5h, a5l)
      __builtin_amdgcn_s_setprio(0);
      __builtin_amdgcn_s_barrier();
    }
    // ---------- P3 ----------
    {
      bf16x8 a6h = LD8(lA, aoff[6][0]), a6l = LD8(lA, aoff[6][1]);
      bf16x8 a7h = LD8(lA, aoff[7][0]), a7l = LD8(lA, aoff[7][1]);
      if (pf) {
        GLOAD16(gBn + 2 * rstep, dBq + 2 * 8192);
        GLOAD16(gBn + 3 * rstep, dBq + 3 * 8192);
      }
      __builtin_amdgcn_s_barrier();
      __builtin_amdgcn_s_setprio(1);
      MFMA_PAIR(6, 7, a6h, a6l, a7h, a7l)
      __builtin_amdgcn_s_setprio(0);
      __builtin_amdgcn_s_barrier();
    }
  }

  // ---- epilogue (C/D: col=lane&15, row=(lane>>4)*4+reg; m89-verified) ----
#pragma unroll
  for (int j = 0; j < 4; ++j) {
    const int col = bn + wc + j * 16 + fr;
    int lc = col;
    const float* bp = b0;
    ushort* ph = Ch0;
    ushort* pl = Cl0;
    if (NSEG == 3) {
      const int seg = col >> 10;
      lc = col & 1023;
      bp = (seg == 0) ? b0 : (seg == 1 ? b1 : b2);
      ph = (seg == 0) ? Ch0 : (seg == 1 ? Ch1 : Ch2);
      pl = (seg == 0) ? Cl0 : (seg == 1 ? Cl1 : Cl2);
    }
    const float bi = HAS_BIAS ? bp[lc] : 0.0f;
#pragma unroll
    for (int i = 0; i < 8; ++i) {
#pragma unroll
      for (int r = 0; r < 4; ++r) {
        const int row = bm + wr + i * 16 + fc * 4 + r;
        float o = acc[i][j][r] + bi;
        if (RELU) o = fmaxf(o, 0.0f);
        if (WRITE_F32) {
          Cf[cof + (size_t)row * N + col] = o;
        } else {
          ushort hh, ll;
          split(o, hh, ll);
          const size_t idx = (size_t)row * ostride + lc;
          ph[idx] = hh;
          pl[idx] = ll;
        }
      }
    }
  }
#undef MFMA6
#undef MFMA_PAIR
}

// ---------------- 128x128 m97-style bf16x3 GEMM (N=1024 cases) ---------------
template <bool HAS_BIAS, bool RELU, bool HAS_RES, bool WRITE_F32, bool EMIT_BF16>
__global__ __launch_bounds__(256, 2) void gemm_bf16x3(
    const ushort* __restrict__ Ah, const ushort* __restrict__ Al,
    const ushort* __restrict__ Bth, const ushort* __restrict__ Btl,
    const float* __restrict__ bias, const float* Res,
    float* Cf, ushort* __restrict__ Ch, ushort* __restrict__ Cl,
    int N, int K, long long sA, long long sB, long long sC) {
  __shared__ __align__(16) ushort sAh[128 * 32];
  __shared__ __align__(16) ushort sAl[128 * 32];
  __shared__ __align__(16) ushort sBh[128 * 32];
  __shared__ __align__(16) ushort sBl[128 * 32];

  const int bz = blockIdx.z;
  const size_t aof = (size_t)bz * sA, bof = (size_t)bz * sB, cof = (size_t)bz * sC;

  const int gx = gridDim.x;
  const int nwg = gx * gridDim.y;
  int lin = blockIdx.y * gx + blockIdx.x;
  lin = (lin & 7) * (nwg >> 3) + (lin >> 3);
  const int bm = (lin / gx) * 128;
  const int bn = (lin % gx) * 128;

  const int tid = threadIdx.x, w = tid >> 6, lane = tid & 63;
  const int wr = (w >> 1) * 64, wc = (w & 1) * 64;

  const int c0 = w * 2, c1 = c0 + 1;
  const int r0 = c0 * 16 + (lane >> 2);
  const int r1 = r0 + 16;
  const int kc = ((lane & 3) ^ (r0 & 3)) * 8;
  const size_t gA0 = aof + (size_t)(bm + r0) * K + kc;
  const size_t gA1 = aof + (size_t)(bm + r1) * K + kc;
  const size_t gB0 = bof + (size_t)(bn + r0) * K + kc;
  const size_t gB1 = bof + (size_t)(bn + r1) * K + kc;
  ushort* dA0 = sAh + c0 * 512; ushort* dA1 = sAh + c1 * 512;
  ushort* dA2 = sAl + c0 * 512; ushort* dA3 = sAl + c1 * 512;
  ushort* dB0 = sBh + c0 * 512; ushort* dB1 = sBh + c1 * 512;
  ushort* dB2 = sBl + c0 * 512; ushort* dB3 = sBl + c1 * 512;

  const int fr = lane & 15, fc = lane >> 4;
  int aoffB[4], boffB[4];
#pragma unroll
  for (int i = 0; i < 4; ++i) {
    const int ra = wr + i * 16 + fr;
    aoffB[i] = ra * 64 + ((fc ^ (ra & 3)) * 16);
    const int rb = wc + i * 16 + fr;
    boffB[i] = rb * 64 + ((fc ^ (rb & 3)) * 16);
  }

  f32x4 acc[4][4];
  const f32x4 zero = {0.f, 0.f, 0.f, 0.f};
#pragma unroll
  for (int i = 0; i < 4; ++i)
#pragma unroll
    for (int j = 0; j < 4; ++j) acc[i][j] = zero;

  for (int kk = 0; kk < K; kk += 32) {
    GLOAD16(Ah + gA0 + kk, dA0);
    GLOAD16(Ah + gA1 + kk, dA1);
    GLOAD16(Al + gA0 + kk, dA2);
    GLOAD16(Al + gA1 + kk, dA3);
    GLOAD16(Bth + gB0 + kk, dB0);
    GLOAD16(Bth + gB1 + kk, dB1);
    GLOAD16(Btl + gB0 + kk, dB2);
    GLOAD16(Btl + gB1 + kk, dB3);
    __syncthreads();

    bf16x8 fah[4], fal[4], fbh[4], fbl[4];
#pragma unroll
    for (int i = 0; i < 4; ++i) {
      fah[i] = LD8((const char*)sAh, aoffB[i]);
      fal[i] = LD8((const char*)sAl, aoffB[i]);
      fbh[i] = LD8((const char*)sBh, boffB[i]);
      fbl[i] = LD8((const char*)sBl, boffB[i]);
    }
    __syncthreads();

#pragma unroll
    for (int i = 0; i < 4; ++i)
#pragma unroll
      for (int j = 0; j < 4; ++j) {
        acc[i][j] = __builtin_amdgcn_mfma_f32_16x16x32_bf16(fah[i], fbh[j], acc[i][j], 0, 0, 0);
        acc[i][j] = __builtin_amdgcn_mfma_f32_16x16x32_bf16(fah[i], fbl[j], acc[i][j], 0, 0, 0);
        acc[i][j] = __builtin_amdgcn_mfma_f32_16x16x32_bf16(fal[i], fbh[j], acc[i][j], 0, 0, 0);
      }
  }

#pragma unroll
  for (int j = 0; j < 4; ++j) {
    const int col = bn + wc + j * 16 + fr;
    const float bi = HAS_BIAS ? bias[col] : 0.0f;
#pragma unroll
    for (int i = 0; i < 4; ++i) {
#pragma unroll
      for (int r = 0; r < 4; ++r) {
        const int row = bm + wr + i * 16 + fc * 4 + r;
        float o = acc[i][j][r] + bi;
        if (RELU) o = fmaxf(o, 0.0f);
        const size_t idx = cof + (size_t)row * N + col;
        if (HAS_RES) o += Res[idx];
        if (WRITE_F32) Cf[idx] = o;
        if (EMIT_BF16) {
          ushort h, l;
          split(o, h, l);
          Ch[idx] = h;
          Cl[idx] = l;
        }
      }
    }
  }
}

// ============================================================================
extern "C" void kernel_launch(void* const* d_in, const int* in_sizes, int n_in,
                              void* d_out, int out_size, void* d_ws, size_t ws_size,
                              hipStream_t stream) {
  const float* x     = (const float*)d_in[0];
  const float* ln1_w = (const float*)d_in[1];
  const float* ln1_b = (const float*)d_in[2];
  const float* Wq    = (const float*)d_in[3];
  const float* bq    = (const float*)d_in[4];
  const float* Wk    = (const float*)d_in[5];
  const float* bk    = (const float*)d_in[6];
  const float* Wv    = (const float*)d_in[7];
  const float* bv    = (const float*)d_in[8];
  const float* Wo    = (const float*)d_in[9];
  const float* bo    = (const float*)d_in[10];
  const float* W1    = (const float*)d_in[11];
  const float* b1    = (const float*)d_in[12];
  const float* W2    = (const float*)d_in[13];
  const float* b2    = (const float*)d_in[14];
  const float* ln2_w = (const float*)d_in[15];
  const float* ln2_b = (const float*)d_in[16];
  float* out = (float*)d_out;
  char* W = (char*)d_ws;

  // Workspace (MB offsets, 192MB peak). Lifetimes audited disjoint:
  //  1 tc Wq/Wk/Wv -> wqkv[32,44)      2 LN1 -> h1[0,32)
  //  3 QKV(gemm256) -> q[64,96) k[96,128) v[128,160)
  //  4 tbf v -> vT[160,192)            5 scores -> scf[0,64)  (h1,wqkv dead)
  //  6 softmax -> attn[64,128)  (q,k dead)
  //  7 ctx(128^2) -> cx[128,160) (v dead)
  //  8 tc Wo -> wo[0,4) (scf dead)     9 Wo(128^2) -> out
  // 10 LN2 -> h2[4,36)               11 tc W1 -> w1[36,52)
  // 12 FFN1(gemm256) -> t1[64,192) (attn,cx,vT dead)
  // 13 tc W2 -> w2[0,16) (wo,h2 dead) 14 FFN2(128^2) -> out
  auto U = [&](size_t mb) { return (ushort*)(W + (mb << 20)); };
  auto F = [&](size_t mb) { return (float*)(W + (mb << 20)); };
  ushort *h1h = U(0),   *h1l = U(16);
  ushort *wqkvh = U(32), *wqkvl = U(38);
  ushort *qh  = U(64),  *ql  = U(80);
  ushort *kh  = U(96),  *kl  = U(112);
  ushort *vh  = U(128), *vl  = U(144);
  ushort *vth = U(160), *vtl = U(176);
  float  *scf = F(0);
  ushort *ath = U(64),  *atl = U(96);
  ushort *cxh = U(128), *cxl = U(144);
  ushort *woh = U(0),   *wol = U(2);
  ushort *h2h = U(4),   *h2l = U(20);
  ushort *w1h = U(36),  *w1l = U(44);
  ushort *w2h = U(0),   *w2l = U(8);
  ushort *t1h = U(64),  *t1l = U(128);

  const long long SD = (long long)S * D, SS = (long long)S * S;
  dim3 tb(256);

  // 1. QKV weights -> concat [3072][1024] bf16 h/l
  transpose_conv<<<dim3(32, 32, 1), tb, 0, stream>>>(Wq, wqkvh, wqkvl, D, D, 0, 0);
  transpose_conv<<<dim3(32, 32, 1), tb, 0, stream>>>(Wk, wqkvh + (size_t)D * D,
                                                     wqkvl + (size_t)D * D, D, D, 0, 0);
  transpose_conv<<<dim3(32, 32, 1), tb, 0, stream>>>(Wv, wqkvh + 2 * (size_t)D * D,
                                                     wqkvl + 2 * (size_t)D * D, D, D, 0, 0);

  // 2. h1 = LN1(x)
  ln_kernel<<<M, tb, 0, stream>>>(x, ln1_w, ln1_b, h1h, h1l);

  // 3. fused QKV: [8192][3072] -> q,k,v bf16 h/l
  gemm256<true, false, false, 3><<<dim3(12, 32, 1), 512, 0, stream>>>(
      h1h, h1l, wqkvh, wqkvl, bq, bk, bv, nullptr,
      qh, ql, kh, kl, vh, vl, 3072, D, D, 0, 0, 0);

  // 4. vT per batch: [2048][1024] -> [1024][2048]
  transpose_bf<<<dim3(32, 64, NB), tb, 0, stream>>>(vh, vl, vth, vtl, S, D, SD, SD);

  // 5. scores = q @ k^T (fp32), batched
  gemm256<false, false, true, 1><<<dim3(8, 8, NB), 512, 0, stream>>>(
      qh, ql, kh, kl, nullptr, nullptr, nullptr, scf,
      nullptr, nullptr, nullptr, nullptr, nullptr, nullptr,
      S, D, S, SD, SD, SS);

  // 6. attn = softmax(scores/32) -> bf16 h/l
  softmax_kernel<<<M, tb, 0, stream>>>(scf, ath, atl);

  // 7. ctx = attn @ v (128^2 kernel), K=2048
  gemm_bf16x3<false, false, false, false, true><<<dim3(8, 16, NB), tb, 0, stream>>>(
      ath, atl, vth, vtl, nullptr, nullptr, nullptr, cxh, cxl, D, S, SS, SD, SD);

  // 8-9. out = x + ctx @ Wo + bo
  transpose_conv<<<dim3(32, 32, 1), tb, 0, stream>>>(Wo, woh, wol, D, D, 0, 0);
  gemm_bf16x3<true, false, true, true, false><<<dim3(8, 64, 1), tb, 0, stream>>>(
      cxh, cxl, woh, wol, bo, x, out, nullptr, nullptr, D, D, 0, 0, 0);

  // 10. h2 = LN2(out)
  ln_kernel<<<M, tb, 0, stream>>>(out, ln2_w, ln2_b, h2h, h2l);

  // 11. W1^T
  transpose_conv<<<dim3(128, 32, 1), tb, 0, stream>>>(W1, w1h, w1l, D, DFF, 0, 0);

  // 12. t1 = relu(h2 @ W1 + b1) -> bf16 h/l
  gemm256<true, true, false, 1><<<dim3(16, 32, 1), 512, 0, stream>>>(
      h2h, h2l, w1h, w1l, b1, nullptr, nullptr, nullptr,
      t1h, t1l, nullptr, nullptr, nullptr, nullptr, DFF, D, DFF, 0, 0, 0);

  // 13. W2^T
  transpose_conv<<<dim3(32, 128, 1), tb, 0, stream>>>(W2, w2h, w2l, DFF, D, 0, 0);

  // 14. out = out + t1 @ W2 + b2 (128^2 kernel), K=4096
  gemm_bf16x3<true, false, true, true, false><<<dim3(8, 64, 1), tb, 0, stream>>>(
      t1h, t1l, w2h, w2l, b2, out, out, nullptr, nullptr, D, DFF, 0, 0, 0);
}

// Round 6
// 1062.256 us; speedup vs baseline: 1.0116x; 1.0116x over previous
//
#include <hip/hip_runtime.h>

// ============================================================================
// TinyTransformerBlock via split-precision bf16x3 MFMA (gfx950).
// C = ah*bh + ah*bl + al*bh in fp32 AGPRs (al*bl dropped, ~2^-18 rel).
// R6: deep-prefetch pipeline — ALL 8 global_load_lds for tile t+1 issued at
// start of tile t (full-tile latency cover), counted vmcnt(8), 5 (256^2) /
// 3 (128^2) barriers per tile. Two engines, same schedule:
//  - gemm256: 256x256, 8 waves, 128KB LDS (1 block/CU) -> scores, FFN1
//  - gemm128p: 128x128, 4 waves, 64KB LDS (2 blocks/CU) -> QKV, ctx, Wo, FFN2
// LDS rows = 128B [hi|lo] x 4 16B-slots each, slot' = slot^(row&7) (R5-verified:
// bank conflicts == 0). XCD-chunked block swizzle (nwg%8==0 everywhere).
// ============================================================================

#define EPS 1e-5f
constexpr int D   = 1024;
constexpr int DFF = 4096;
constexpr int NB  = 4;
constexpr int S   = 2048;
constexpr int M   = NB * S;  // 8192

typedef __bf16 bf16x8 __attribute__((ext_vector_type(8)));
typedef float  f32x4  __attribute__((ext_vector_type(4)));

__device__ __forceinline__ ushort f2bf(float f) {  // RTNE to bf16
  uint u = __builtin_bit_cast(uint, f);
  return (ushort)((u + 0x7fffu + ((u >> 16) & 1u)) >> 16);
}
__device__ __forceinline__ float bf2f(ushort h) {
  return __builtin_bit_cast(float, (uint)h << 16);
}
__device__ __forceinline__ void split(float f, ushort& h, ushort& l) {
  h = f2bf(f);
  l = f2bf(f - bf2f(h));
}

#define GLOAD16(g, l)                                                     \
  __builtin_amdgcn_global_load_lds(                                       \
      (const __attribute__((address_space(1))) void*)(g),                 \
      (__attribute__((address_space(3))) void*)(l), 16, 0, 0)

#define LD8(base, off) \
  __builtin_bit_cast(bf16x8, *reinterpret_cast<const uint4*>((base) + (off)))

#define MFMA6(ii, xh, xl, jj)                                                 \
  acc[ii][jj] = __builtin_amdgcn_mfma_f32_16x16x32_bf16(xh, bh##jj, acc[ii][jj], 0, 0, 0); \
  acc[ii][jj] = __builtin_amdgcn_mfma_f32_16x16x32_bf16(xh, bl##jj, acc[ii][jj], 0, 0, 0); \
  acc[ii][jj] = __builtin_amdgcn_mfma_f32_16x16x32_bf16(xl, bh##jj, acc[ii][jj], 0, 0, 0);

#define MFMA_PAIR(i0, i1, xh, xl, yh, yl)                                     \
  MFMA6(i0, xh, xl, 0) MFMA6(i1, yh, yl, 0)                                   \
  MFMA6(i0, xh, xl, 1) MFMA6(i1, yh, yl, 1)                                   \
  MFMA6(i0, xh, xl, 2) MFMA6(i1, yh, yl, 2)                                   \
  MFMA6(i0, xh, xl, 3) MFMA6(i1, yh, yl, 3)

// ---------------- LayerNorm -> bf16 hi/lo ------------------------------------
__global__ __launch_bounds__(256) void ln_kernel(const float* __restrict__ x,
                                                 const float* __restrict__ w,
                                                 const float* __restrict__ b,
                                                 ushort* __restrict__ oh,
                                                 ushort* __restrict__ ol) {
  const int row = blockIdx.x;
  const int t   = threadIdx.x;
  const float4 v = reinterpret_cast<const float4*>(x + (size_t)row * D)[t];
  float s  = v.x + v.y + v.z + v.w;
  float sq = v.x * v.x + v.y * v.y + v.z * v.z + v.w * v.w;
#pragma unroll
  for (int off = 32; off > 0; off >>= 1) {
    s  += __shfl_down(s, off);
    sq += __shfl_down(sq, off);
  }
  __shared__ float red[8];
  if ((t & 63) == 0) { red[t >> 6] = s; red[(t >> 6) + 4] = sq; }
  __syncthreads();
  if (t == 0) {
    float ts = red[0] + red[1] + red[2] + red[3];
    float tq = red[4] + red[5] + red[6] + red[7];
    float mu  = ts * (1.0f / D);
    float var = tq * (1.0f / D) - mu * mu;
    red[0] = mu;
    red[1] = rsqrtf(var + EPS);
  }
  __syncthreads();
  const float mu = red[0], rs = red[1];
  const float4 wv = reinterpret_cast<const float4*>(w)[t];
  const float4 bv = reinterpret_cast<const float4*>(b)[t];
  float o0 = (v.x - mu) * rs * wv.x + bv.x;
  float o1 = (v.y - mu) * rs * wv.y + bv.y;
  float o2 = (v.z - mu) * rs * wv.z + bv.z;
  float o3 = (v.w - mu) * rs * wv.w + bv.w;
  ushort4 hh, ll;
  split(o0, hh.x, ll.x); split(o1, hh.y, ll.y);
  split(o2, hh.z, ll.z); split(o3, hh.w, ll.w);
  *reinterpret_cast<ushort4*>(oh + (size_t)row * D + t * 4) = hh;
  *reinterpret_cast<ushort4*>(ol + (size_t)row * D + t * 4) = ll;
}

// ---------------- Softmax (scale folded) -> bf16 hi/lo -----------------------
__global__ __launch_bounds__(256) void softmax_kernel(const float* __restrict__ sc,
                                                      ushort* __restrict__ oh,
                                                      ushort* __restrict__ ol) {
  const size_t row = blockIdx.x;
  const float* p = sc + row * (size_t)S;
  const int t = threadIdx.x;
  constexpr float scale = 0.03125f;  // 1/sqrt(1024)
  float4 a = reinterpret_cast<const float4*>(p)[t];
  float4 b = reinterpret_cast<const float4*>(p)[t + 256];
  a.x *= scale; a.y *= scale; a.z *= scale; a.w *= scale;
  b.x *= scale; b.y *= scale; b.z *= scale; b.w *= scale;
  float m = fmaxf(fmaxf(fmaxf(a.x, a.y), fmaxf(a.z, a.w)),
                  fmaxf(fmaxf(b.x, b.y), fmaxf(b.z, b.w)));
#pragma unroll
  for (int off = 32; off > 0; off >>= 1) m = fmaxf(m, __shfl_xor(m, off));
  __shared__ float redm[4];
  __shared__ float reds[4];
  if ((t & 63) == 0) redm[t >> 6] = m;
  __syncthreads();
  m = fmaxf(fmaxf(redm[0], redm[1]), fmaxf(redm[2], redm[3]));
  a.x = __expf(a.x - m); a.y = __expf(a.y - m);
  a.z = __expf(a.z - m); a.w = __expf(a.w - m);
  b.x = __expf(b.x - m); b.y = __expf(b.y - m);
  b.z = __expf(b.z - m); b.w = __expf(b.w - m);
  float s = a.x + a.y + a.z + a.w + b.x + b.y + b.z + b.w;
#pragma unroll
  for (int off = 32; off > 0; off >>= 1) s += __shfl_xor(s, off);
  if ((t & 63) == 0) reds[t >> 6] = s;
  __syncthreads();
  s = reds[0] + reds[1] + reds[2] + reds[3];
  const float inv = 1.0f / s;
  ushort4 ha, la, hb, lb;
  split(a.x * inv, ha.x, la.x); split(a.y * inv, ha.y, la.y);
  split(a.z * inv, ha.z, la.z); split(a.w * inv, ha.w, la.w);
  split(b.x * inv, hb.x, lb.x); split(b.y * inv, hb.y, lb.y);
  split(b.z * inv, hb.z, lb.z); split(b.w * inv, hb.w, lb.w);
  ushort* ph = oh + row * (size_t)S;
  ushort* pl = ol + row * (size_t)S;
  *reinterpret_cast<ushort4*>(ph + t * 4)        = ha;
  *reinterpret_cast<ushort4*>(ph + 1024 + t * 4) = hb;
  *reinterpret_cast<ushort4*>(pl + t * 4)        = la;
  *reinterpret_cast<ushort4*>(pl + 1024 + t * 4) = lb;
}

// ---------------- Transpose fp32 [R][C] -> bf16 hi/lo [C][R] -----------------
__global__ __launch_bounds__(256) void transpose_conv(const float* __restrict__ in,
                                                      ushort* __restrict__ oh,
                                                      ushort* __restrict__ ol,
                                                      int R, int C,
                                                      long long sIn, long long sOut) {
  __shared__ float tile[32][33];
  const int bz = blockIdx.z;
  const float* ip = in + (size_t)bz * sIn;
  ushort* ph = oh + (size_t)bz * sOut;
  ushort* pl = ol + (size_t)bz * sOut;
  const int c0 = blockIdx.x * 32, r0 = blockIdx.y * 32;
  const int tx = threadIdx.x & 31, ty = threadIdx.x >> 5;
#pragma unroll
  for (int i = 0; i < 4; ++i)
    tile[ty + 8 * i][tx] = ip[(size_t)(r0 + ty + 8 * i) * C + c0 + tx];
  __syncthreads();
#pragma unroll
  for (int i = 0; i < 4; ++i) {
    float v = tile[tx][ty + 8 * i];
    ushort h, l;
    split(v, h, l);
    const size_t o = (size_t)(c0 + ty + 8 * i) * R + r0 + tx;
    ph[o] = h;
    pl[o] = l;
  }
}

// ---------------- Transpose ushort pair [R][C] -> [C][R] ---------------------
__global__ __launch_bounds__(256) void transpose_bf(const ushort* __restrict__ ih,
                                                    const ushort* __restrict__ il,
                                                    ushort* __restrict__ oh,
                                                    ushort* __restrict__ ol,
                                                    int R, int C,
                                                    long long sIn, long long sOut) {
  __shared__ ushort th[32][34];
  __shared__ ushort tl[32][34];
  const int bz = blockIdx.z;
  const ushort* ph = ih + (size_t)bz * sIn;
  const ushort* pl = il + (size_t)bz * sIn;
  ushort* qh = oh + (size_t)bz * sOut;
  ushort* ql = ol + (size_t)bz * sOut;
  const int c0 = blockIdx.x * 32, r0 = blockIdx.y * 32;
  const int tx = threadIdx.x & 31, ty = threadIdx.x >> 5;
#pragma unroll
  for (int i = 0; i < 4; ++i) {
    const size_t src = (size_t)(r0 + ty + 8 * i) * C + c0 + tx;
    th[ty + 8 * i][tx] = ph[src];
    tl[ty + 8 * i][tx] = pl[src];
  }
  __syncthreads();
#pragma unroll
  for (int i = 0; i < 4; ++i) {
    const size_t o = (size_t)(c0 + ty + 8 * i) * R + r0 + tx;
    qh[o] = th[tx][ty + 8 * i];
    ql[o] = tl[tx][ty + 8 * i];
  }
}

// ================= 256x256 deep-prefetch bf16x3 GEMM =========================
// A:[M][K] h/l.  Bt:[N][K] h/l.  8 waves (2x4), per-wave 128x64 out.
// All 8 GLOADs for tile t+1 issued at start of tile t; vmcnt(8) counted wait.
template <bool HAS_BIAS, bool RELU, bool WRITE_F32>
__global__ __launch_bounds__(512, 2) void gemm256(
    const ushort* __restrict__ Ah, const ushort* __restrict__ Al,
    const ushort* __restrict__ Bth, const ushort* __restrict__ Btl,
    const float* __restrict__ bias, float* __restrict__ Cf,
    ushort* __restrict__ Ch, ushort* __restrict__ Cl,
    int N, int K, int ostride, long long sA, long long sB, long long sC) {
  __shared__ __align__(16) ushort sAb[2][256 * 64];
  __shared__ __align__(16) ushort sBb[2][256 * 64];

  const int bz = blockIdx.z;
  const size_t aof = (size_t)bz * sA, bof = (size_t)bz * sB, cof = (size_t)bz * sC;

  const int gx = gridDim.x;
  const int nwg = gx * gridDim.y;
  int lin = blockIdx.y * gx + blockIdx.x;
  lin = (lin & 7) * (nwg >> 3) + (lin >> 3);
  const int bm = (lin / gx) * 256;
  const int bn = (lin % gx) * 256;

  const int tid = threadIdx.x;
  const int lane = tid & 63, w = tid >> 6;
  const int wr = (w >> 2) * 128, wc = (w & 3) * 64;
  const int fr = lane & 15, fc = lane >> 4;

  // staging decode (R5-verified, bank-conflict-free)
  const int srow  = tid >> 3;                 // 0..63
  const int slot  = (tid & 7) ^ (srow & 7);
  const int hilo  = slot >> 2;
  const int kg    = slot & 3;
  const ushort* gA = (hilo ? Al : Ah) + aof + (size_t)(bm + srow) * K + kg * 8;
  const ushort* gB = (hilo ? Btl : Bth) + bof + (size_t)(bn + srow) * K + kg * 8;
  const size_t rstep = (size_t)64 * K;
  const int dsto = tid * 16;

  int aoff[8][2], boff[4][2];
#pragma unroll
  for (int i = 0; i < 8; ++i) {
    const int row = wr + i * 16 + fr;
#pragma unroll
    for (int h = 0; h < 2; ++h)
      aoff[i][h] = row * 128 + (((h * 4 + fc) ^ (row & 7)) * 16);
  }
#pragma unroll
  for (int j = 0; j < 4; ++j) {
    const int row = wc + j * 16 + fr;
#pragma unroll
    for (int h = 0; h < 2; ++h)
      boff[j][h] = row * 128 + (((h * 4 + fc) ^ (row & 7)) * 16);
  }

  f32x4 acc[8][4];
  const f32x4 zero = {0.f, 0.f, 0.f, 0.f};
#pragma unroll
  for (int i = 0; i < 8; ++i)
#pragma unroll
    for (int j = 0; j < 4; ++j) acc[i][j] = zero;

  const int nt = K >> 5;

  {  // prologue: stage tile 0 -> buf 0
    char* dA = (char*)(&sAb[0][0]) + dsto;
    char* dB = (char*)(&sBb[0][0]) + dsto;
#pragma unroll
    for (int rr = 0; rr < 4; ++rr) {
      GLOAD16(gA + rr * rstep, dA + rr * 8192);
      GLOAD16(gB + rr * rstep, dB + rr * 8192);
    }
  }

  for (int t = 0; t < nt; ++t) {
    const int p = t & 1, q = p ^ 1;
    const char* lA = (const char*)(&sAb[p][0]);
    const char* lB = (const char*)(&sBb[p][0]);
    // issue ALL staging for tile t+1 now (buf q is idle from here)
    if (t + 1 < nt) {
      const ushort* gAn = gA + ((t + 1) << 5);
      const ushort* gBn = gB + ((t + 1) << 5);
      char* dAq = (char*)(&sAb[q][0]) + dsto;
      char* dBq = (char*)(&sBb[q][0]) + dsto;
#pragma unroll
      for (int rr = 0; rr < 4; ++rr) {
        GLOAD16(gAn + rr * rstep, dAq + rr * 8192);
        GLOAD16(gBn + rr * rstep, dBq + rr * 8192);
      }
      asm volatile("s_waitcnt vmcnt(8)" ::: "memory");  // tile t's loads done
    } else {
      asm volatile("s_waitcnt vmcnt(0)" ::: "memory");
    }
    __builtin_amdgcn_s_barrier();

    // P0: B full + A rows 0,1
    bf16x8 bh0 = LD8(lB, boff[0][0]), bl0 = LD8(lB, boff[0][1]);
    bf16x8 bh1 = LD8(lB, boff[1][0]), bl1 = LD8(lB, boff[1][1]);
    bf16x8 bh2 = LD8(lB, boff[2][0]), bl2 = LD8(lB, boff[2][1]);
    bf16x8 bh3 = LD8(lB, boff[3][0]), bl3 = LD8(lB, boff[3][1]);
    bf16x8 a0h = LD8(lA, aoff[0][0]), a0l = LD8(lA, aoff[0][1]);
    bf16x8 a1h = LD8(lA, aoff[1][0]), a1l = LD8(lA, aoff[1][1]);
    __builtin_amdgcn_s_setprio(1);
    MFMA_PAIR(0, 1, a0h, a0l, a1h, a1l)
    __builtin_amdgcn_s_setprio(0);
    __builtin_amdgcn_s_barrier();
    {  // P1
      bf16x8 a2h = LD8(lA, aoff[2][0]), a2l = LD8(lA, aoff[2][1]);
      bf16x8 a3h = LD8(lA, aoff[3][0]), a3l = LD8(lA, aoff[3][1]);
      __builtin_amdgcn_s_setprio(1);
      MFMA_PAIR(2, 3, a2h, a2l, a3h, a3l)
      __builtin_amdgcn_s_setprio(0);
      __builtin_amdgcn_s_barrier();
    }
    {  // P2
      bf16x8 a4h = LD8(lA, aoff[4][0]), a4l = LD8(lA, aoff[4][1]);
      bf16x8 a5h = LD8(lA, aoff[5][0]), a5l = LD8(lA, aoff[5][1]);
      __builtin_amdgcn_s_setprio(1);
      MFMA_PAIR(4, 5, a4h, a4l, a5h, a5l)
      __builtin_amdgcn_s_setprio(0);
      __builtin_amdgcn_s_barrier();
    }
    {  // P3 (final barrier guards buf p against next tile's staging)
      bf16x8 a6h = LD8(lA, aoff[6][0]), a6l = LD8(lA, aoff[6][1]);
      bf16x8 a7h = LD8(lA, aoff[7][0]), a7l = LD8(lA, aoff[7][1]);
      __builtin_amdgcn_s_setprio(1);
      MFMA_PAIR(6, 7, a6h, a6l, a7h, a7l)
      __builtin_amdgcn_s_setprio(0);
      __builtin_amdgcn_s_barrier();
    }
  }

#pragma unroll
  for (int j = 0; j < 4; ++j) {
    const int col = bn + wc + j * 16 + fr;
    const float bi = HAS_BIAS ? bias[col] : 0.0f;
#pragma unroll
    for (int i = 0; i < 8; ++i) {
#pragma unroll
      for (int r = 0; r < 4; ++r) {
        const int row = bm + wr + i * 16 + fc * 4 + r;
        float o = acc[i][j][r] + bi;
        if (RELU) o = fmaxf(o, 0.0f);
        if (WRITE_F32) {
          Cf[cof + (size_t)row * N + col] = o;
        } else {
          ushort hh, ll;
          split(o, hh, ll);
          const size_t idx = (size_t)row * ostride + col;
          Ch[idx] = hh;
          Cl[idx] = ll;
        }
      }
    }
  }
}

// ================= 128x128 deep-prefetch bf16x3 GEMM (2 blocks/CU) ===========
// 4 waves (2x2, 64x64 out each). 64KB LDS. Same schedule, 2 MFMA phases/tile.
template <bool HAS_BIAS, bool RELU, bool HAS_RES, bool WRITE_F32, bool EMIT_BF16>
__global__ __launch_bounds__(256, 2) void gemm128p(
    const ushort* __restrict__ Ah, const ushort* __restrict__ Al,
    const ushort* __restrict__ Bth, const ushort* __restrict__ Btl,
    const float* __restrict__ bias, const float* Res,
    float* Cf, ushort* __restrict__ Ch, ushort* __restrict__ Cl,
    int N, int K, long long sA, long long sB, long long sC) {
  __shared__ __align__(16) ushort sAb[2][128 * 64];
  __shared__ __align__(16) ushort sBb[2][128 * 64];

  const int bz = blockIdx.z;
  const size_t aof = (size_t)bz * sA, bof = (size_t)bz * sB, cof = (size_t)bz * sC;

  const int gx = gridDim.x;
  const int nwg = gx * gridDim.y;
  int lin = blockIdx.y * gx + blockIdx.x;
  lin = (lin & 7) * (nwg >> 3) + (lin >> 3);
  const int bm = (lin / gx) * 128;
  const int bn = (lin % gx) * 128;

  const int tid = threadIdx.x;
  const int lane = tid & 63, w = tid >> 6;
  const int wr = (w >> 1) * 64, wc = (w & 1) * 64;
  const int fr = lane & 15, fc = lane >> 4;

  // staging: 4 rounds of 32 rows per operand (row&7 == srow&7, rounds are x32)
  const int srow  = tid >> 3;                 // 0..31
  const int slot  = (tid & 7) ^ (srow & 7);
  const int hilo  = slot >> 2;
  const int kg    = slot & 3;
  const ushort* gA = (hilo ? Al : Ah) + aof + (size_t)(bm + srow) * K + kg * 8;
  const ushort* gB = (hilo ? Btl : Bth) + bof + (size_t)(bn + srow) * K + kg * 8;
  const size_t rstep = (size_t)32 * K;
  const int dsto = tid * 16;

  int aoff[4][2], boff[4][2];
#pragma unroll
  for (int i = 0; i < 4; ++i) {
    const int ra = wr + i * 16 + fr;
    const int rb = wc + i * 16 + fr;
#pragma unroll
    for (int h = 0; h < 2; ++h) {
      aoff[i][h] = ra * 128 + (((h * 4 + fc) ^ (ra & 7)) * 16);
      boff[i][h] = rb * 128 + (((h * 4 + fc) ^ (rb & 7)) * 16);
    }
  }

  f32x4 acc[4][4];
  const f32x4 zero = {0.f, 0.f, 0.f, 0.f};
#pragma unroll
  for (int i = 0; i < 4; ++i)
#pragma unroll
    for (int j = 0; j < 4; ++j) acc[i][j] = zero;

  const int nt = K >> 5;

  {  // prologue
    char* dA = (char*)(&sAb[0][0]) + dsto;
    char* dB = (char*)(&sBb[0][0]) + dsto;
#pragma unroll
    for (int rr = 0; rr < 4; ++rr) {
      GLOAD16(gA + rr * rstep, dA + rr * 4096);
      GLOAD16(gB + rr * rstep, dB + rr * 4096);
    }
  }

  for (int t = 0; t < nt; ++t) {
    const int p = t & 1, q = p ^ 1;
    const char* lA = (const char*)(&sAb[p][0]);
    const char* lB = (const char*)(&sBb[p][0]);
    if (t + 1 < nt) {
      const ushort* gAn = gA + ((t + 1) << 5);
      const ushort* gBn = gB + ((t + 1) << 5);
      char* dAq = (char*)(&sAb[q][0]) + dsto;
      char* dBq = (char*)(&sBb[q][0]) + dsto;
#pragma unroll
      for (int rr = 0; rr < 4; ++rr) {
        GLOAD16(gAn + rr * rstep, dAq + rr * 4096);
        GLOAD16(gBn + rr * rstep, dBq + rr * 4096);
      }
      asm volatile("s_waitcnt vmcnt(8)" ::: "memory");
    } else {
      asm volatile("s_waitcnt vmcnt(0)" ::: "memory");
    }
    __builtin_amdgcn_s_barrier();

    // P0: B full + A rows 0,1 -> 24 MFMA
    bf16x8 bh0 = LD8(lB, boff[0][0]), bl0 = LD8(lB, boff[0][1]);
    bf16x8 bh1 = LD8(lB, boff[1][0]), bl1 = LD8(lB, boff[1][1]);
    bf16x8 bh2 = LD8(lB, boff[2][0]), bl2 = LD8(lB, boff[2][1]);
    bf16x8 bh3 = LD8(lB, boff[3][0]), bl3 = LD8(lB, boff[3][1]);
    bf16x8 a0h = LD8(lA, aoff[0][0]), a0l = LD8(lA, aoff[0][1]);
    bf16x8 a1h = LD8(lA, aoff[1][0]), a1l = LD8(lA, aoff[1][1]);
    __builtin_amdgcn_s_setprio(1);
    MFMA_PAIR(0, 1, a0h, a0l, a1h, a1l)
    __builtin_amdgcn_s_setprio(0);
    __builtin_amdgcn_s_barrier();
    {  // P1: A rows 2,3 -> 24 MFMA (final barrier guards buf p)
      bf16x8 a2h = LD8(lA, aoff[2][0]), a2l = LD8(lA, aoff[2][1]);
      bf16x8 a3h = LD8(lA, aoff[3][0]), a3l = LD8(lA, aoff[3][1]);
      __builtin_amdgcn_s_setprio(1);
      MFMA_PAIR(2, 3, a2h, a2l, a3h, a3l)
      __builtin_amdgcn_s_setprio(0);
      __builtin_amdgcn_s_barrier();
    }
  }

#pragma unroll
  for (int j = 0; j < 4; ++j) {
    const int col = bn + wc + j * 16 + fr;
    const float bi = HAS_BIAS ? bias[col] : 0.0f;
#pragma unroll
    for (int i = 0; i < 4; ++i) {
#pragma unroll
      for (int r = 0; r < 4; ++r) {
        const int row = bm + wr + i * 16 + fc * 4 + r;
        float o = acc[i][j][r] + bi;
        if (RELU) o = fmaxf(o, 0.0f);
        const size_t idx = cof + (size_t)row * N + col;
        if (HAS_RES) o += Res[idx];
        if (WRITE_F32) Cf[idx] = o;
        if (EMIT_BF16) {
          ushort h, l;
          split(o, h, l);
          Ch[idx] = h;
          Cl[idx] = l;
        }
      }
    }
  }
}

// ============================================================================
extern "C" void kernel_launch(void* const* d_in, const int* in_sizes, int n_in,
                              void* d_out, int out_size, void* d_ws, size_t ws_size,
                              hipStream_t stream) {
  const float* x     = (const float*)d_in[0];
  const float* ln1_w = (const float*)d_in[1];
  const float* ln1_b = (const float*)d_in[2];
  const float* Wq    = (const float*)d_in[3];
  const float* bq    = (const float*)d_in[4];
  const float* Wk    = (const float*)d_in[5];
  const float* bk    = (const float*)d_in[6];
  const float* Wv    = (const float*)d_in[7];
  const float* bv    = (const float*)d_in[8];
  const float* Wo    = (const float*)d_in[9];
  const float* bo    = (const float*)d_in[10];
  const float* W1    = (const float*)d_in[11];
  const float* b1    = (const float*)d_in[12];
  const float* W2    = (const float*)d_in[13];
  const float* b2    = (const float*)d_in[14];
  const float* ln2_w = (const float*)d_in[15];
  const float* ln2_b = (const float*)d_in[16];
  float* out = (float*)d_out;
  char* W = (char*)d_ws;

  // Workspace (MB offsets, 192MB peak; phase lifetimes audited disjoint)
  auto U = [&](size_t mb) { return (ushort*)(W + (mb << 20)); };
  auto F = [&](size_t mb) { return (float*)(W + (mb << 20)); };
  ushort *h1h = U(0),   *h1l = U(16);
  ushort *wqh = U(32),  *wql = U(34);
  ushort *wkh = U(36),  *wkl = U(38);
  ushort *wvh = U(40),  *wvl = U(42);
  ushort *qh  = U(64),  *ql  = U(80);
  ushort *kh  = U(96),  *kl  = U(112);
  ushort *vh  = U(128), *vl  = U(144);
  ushort *vth = U(160), *vtl = U(176);
  float  *scf = F(0);
  ushort *ath = U(64),  *atl = U(96);
  ushort *cxh = U(128), *cxl = U(144);
  ushort *woh = U(0),   *wol = U(2);
  ushort *h2h = U(4),   *h2l = U(20);
  ushort *w1h = U(36),  *w1l = U(44);
  ushort *w2h = U(0),   *w2l = U(8);
  ushort *t1h = U(64),  *t1l = U(128);

  const long long SD = (long long)S * D, SS = (long long)S * S;
  dim3 tb(256);

  // 1. weight transposes (Q,K,V)
  transpose_conv<<<dim3(32, 32, 1), tb, 0, stream>>>(Wq, wqh, wql, D, D, 0, 0);
  transpose_conv<<<dim3(32, 32, 1), tb, 0, stream>>>(Wk, wkh, wkl, D, D, 0, 0);
  transpose_conv<<<dim3(32, 32, 1), tb, 0, stream>>>(Wv, wvh, wvl, D, D, 0, 0);

  // 2. h1 = LN1(x)
  ln_kernel<<<M, tb, 0, stream>>>(x, ln1_w, ln1_b, h1h, h1l);

  // 3-5. q/k/v = h1 @ W + b   (512-block full-fill grids, 2 blocks/CU)
  dim3 g1024(8, 64, 1);
  gemm128p<true, false, false, false, true><<<g1024, tb, 0, stream>>>(
      h1h, h1l, wqh, wql, bq, nullptr, nullptr, qh, ql, D, D, 0, 0, 0);
  gemm128p<true, false, false, false, true><<<g1024, tb, 0, stream>>>(
      h1h, h1l, wkh, wkl, bk, nullptr, nullptr, kh, kl, D, D, 0, 0, 0);
  gemm128p<true, false, false, false, true><<<g1024, tb, 0, stream>>>(
      h1h, h1l, wvh, wvl, bv, nullptr, nullptr, vh, vl, D, D, 0, 0, 0);

  // 6. vT per batch
  transpose_bf<<<dim3(32, 64, NB), tb, 0, stream>>>(vh, vl, vth, vtl, S, D, SD, SD);

  // 7. scores = q @ k^T (fp32), batched (256 blocks, full fill)
  gemm256<false, false, true><<<dim3(8, 8, NB), 512, 0, stream>>>(
      qh, ql, kh, kl, nullptr, scf, nullptr, nullptr, S, D, S, SD, SD, SS);

  // 8. attn = softmax(scores/32) -> bf16 h/l
  softmax_kernel<<<M, tb, 0, stream>>>(scf, ath, atl);

  // 9. ctx = attn @ v, batched K=2048 (512 blocks)
  gemm128p<false, false, false, false, true><<<dim3(8, 16, NB), tb, 0, stream>>>(
      ath, atl, vth, vtl, nullptr, nullptr, nullptr, cxh, cxl, D, S, SS, SD, SD);

  // 10-11. out = x + ctx @ Wo + bo
  transpose_conv<<<dim3(32, 32, 1), tb, 0, stream>>>(Wo, woh, wol, D, D, 0, 0);
  gemm128p<true, false, true, true, false><<<g1024, tb, 0, stream>>>(
      cxh, cxl, woh, wol, bo, x, out, nullptr, nullptr, D, D, 0, 0, 0);

  // 12. h2 = LN2(out)
  ln_kernel<<<M, tb, 0, stream>>>(out, ln2_w, ln2_b, h2h, h2l);

  // 13. W1^T
  transpose_conv<<<dim3(128, 32, 1), tb, 0, stream>>>(W1, w1h, w1l, D, DFF, 0, 0);

  // 14. t1 = relu(h2 @ W1 + b1)  (512 blocks gemm256)
  gemm256<true, true, false><<<dim3(16, 32, 1), 512, 0, stream>>>(
      h2h, h2l, w1h, w1l, b1, nullptr, t1h, t1l, DFF, D, DFF, 0, 0, 0);

  // 15. W2^T
  transpose_conv<<<dim3(32, 128, 1), tb, 0, stream>>>(W2, w2h, w2l, DFF, D, 0, 0);

  // 16. out = out + t1 @ W2 + b2, K=4096 (512 blocks)
  gemm128p<true, false, true, true, false><<<g1024, tb, 0, stream>>>(
      t1h, t1l, w2h, w2l, b2, out, out, nullptr, nullptr, D, DFF, 0, 0, 0);
}